// Round 8
// baseline (84.166 us; speedup 1.0000x reference)
//
#include <hip/hip_runtime.h>
#include <math.h>

// KAN attention: two spline-edge reductions (q,k branches) + bias + softmax(dim=8).
// batch=8, act_in=act_out=2048, C=8 coeffs/edge, N=4.19M edges/branch.
//
// R7 -> R8: R7's wall was the LDS pipe (48 B-reads + 27 shuffles per 1-o step
// = 637 cy x 256 steps/CU = the whole 122us). R8: (1) 2 o's per step so the
// 48 B-reads serve 2 outputs (branch-split phases keep live regs <= ~60 under
// the 64 budget); (2) float2 acc + v_pk_fma_f32: one packed FMA covers both
// o's; scales folded into coef once per step; (3) 7-swizzle fold reduction
// (output lane l holds b=bitrev3(l); softmax reads the permuted slot) instead
// of the 24-swizzle butterfly. sched_barrier(0) per b-iteration retained (the
// R4-R6 spill fix).

#define ACT 2048
#define BATCH 8
#define IBLK 64               // i per block (= lanes of one wave)
#define NIC (ACT / IBLK)      // 32 i-chunks
#define OBLK 64               // o per block
#define NOC (ACT / OBLK)      // 32 o-chunks

typedef float v2f __attribute__((ext_vector_type(2)));

__device__ __forceinline__ v2f fma2(v2f a, v2f b, v2f c) {
  return __builtin_elementwise_fma(a, b, c);
}
__device__ __forceinline__ v2f shflx2(v2f v, int m) {
  v2f r;
  r.x = __shfl_xor(v.x, m);
  r.y = __shfl_xor(v.y, m);
  return r;
}

// ---------------------------------------------------------------------------
// Kernel 1: B-spline basis (Cox-de Boor, k=3, 12 uniform knots at -2.2+0.4j)
// and silu(x) for all (b,i) of both branches.
// Layout: B[ic][b*2+h][il] as float4 (ic=i/64, il=i%64), base[ic][b][il].
// ---------------------------------------------------------------------------
__global__ void kan_precompute(const float* __restrict__ q, const float* __restrict__ k,
                               float4* __restrict__ Bq, float4* __restrict__ Bk,
                               float* __restrict__ baseq, float* __restrict__ basek) {
  int tid = blockIdx.x * blockDim.x + threadIdx.x;
  if (tid >= ACT * BATCH) return;
  int il = tid & (IBLK - 1);
  int b = (tid >> 6) & 7;
  int ic = tid >> 9;
  int i = ic * IBLK + il;
  const float t0 = -2.2f;
  const float h = 0.4f;
  for (int br = 0; br < 2; ++br) {
    const float* xsrc = br ? k : q;
    float4* Bdst = br ? Bk : Bq;
    float* basedst = br ? basek : baseq;
    float x = xsrc[(size_t)b * ACT + i];
    float Bv[11];
#pragma unroll
    for (int j = 0; j < 11; ++j) {
      float tj = t0 + h * (float)j;
      float tj1 = t0 + h * (float)(j + 1);
      Bv[j] = (x >= tj && x < tj1) ? 1.0f : 0.0f;
    }
#pragma unroll
    for (int d = 1; d <= 3; ++d) {
      float inv = 1.0f / (h * (float)d);
#pragma unroll
      for (int j = 0; j + d < 11; ++j) {
        float tj = t0 + h * (float)j;
        float tjd1 = t0 + h * (float)(j + d + 1);
        Bv[j] = (x - tj) * inv * Bv[j] + (tjd1 - x) * inv * Bv[j + 1];
      }
    }
    Bdst[((size_t)ic * 16 + b * 2 + 0) * IBLK + il] = make_float4(Bv[0], Bv[1], Bv[2], Bv[3]);
    Bdst[((size_t)ic * 16 + b * 2 + 1) * IBLK + il] = make_float4(Bv[4], Bv[5], Bv[6], Bv[7]);
    basedst[((size_t)ic * 8 + b) * IBLK + il] = x / (1.0f + expf(-x));
  }
}

// ---------------------------------------------------------------------------
// Kernel 2: main reduction. 1024 blocks x 512 threads, 4 blocks/CU (36 KB
// LDS) -> 32 waves/CU. Block = (ic: 64 i) x (oc: 64 o); wave w handles an
// o-PAIR per step, 4 steps, no barriers in the loop. Per step: q-phase
// (load+scale-fold q coef, 8 b-iters of packed FMA vs LDS B), k-phase (same
// with k), then a 7+3-swizzle fold reduction and a 2-float store per lane<8.
// acc2[b] = {y_o0, y_o1} partial; B element broadcast into both pk lanes.
// ---------------------------------------------------------------------------
__global__ __launch_bounds__(512, 8) void kan_main(
    const float* __restrict__ coef_q, const float* __restrict__ coef_k,
    const float* __restrict__ scale_base, const float* __restrict__ scale_sp,
    const float* __restrict__ mask_q, const float* __restrict__ mask_k,
    const float4* __restrict__ Bq, const float4* __restrict__ Bk,
    const float* __restrict__ baseq, const float* __restrict__ basek,
    float* __restrict__ y_part) {
  __shared__ float4 BsQ[16 * IBLK];   // [(b*2+h)*64 + il]
  __shared__ float4 BsK[16 * IBLK];
  __shared__ float basQ[8 * IBLK];    // [b*64 + il]
  __shared__ float basK[8 * IBLK];

  const int t = threadIdx.x;
  const int l = t & 63;               // lane = i within chunk
  const int w = t >> 6;               // wave index (0..7)
  const int oc = blockIdx.x >> 5;
  const int ic = blockIdx.x & 31;
  const int o0 = oc * OBLK;
  const size_t ibase = (size_t)ic * IBLK + l;

  // ---- stage B/base for both branches (once per block lifetime) ----
  {
    const float4* srcq = Bq + (size_t)ic * 16 * IBLK;
    const float4* srck = Bk + (size_t)ic * 16 * IBLK;
#pragma unroll
    for (int r = 0; r < 2; ++r) {
      BsQ[r * 512 + t] = srcq[r * 512 + t];
      BsK[r * 512 + t] = srck[r * 512 + t];
    }
    if (t < 128) {
      reinterpret_cast<float4*>(basQ)[t] =
          reinterpret_cast<const float4*>(baseq + (size_t)ic * 8 * IBLK)[t];
    } else if (t < 256) {
      reinterpret_cast<float4*>(basK)[t - 128] =
          reinterpret_cast<const float4*>(basek + (size_t)ic * 8 * IBLK)[t - 128];
    }
  }
  __syncthreads();

#pragma unroll 1
  for (int s = 0; s < 4; ++s) {
    const int oa = o0 + w * 8 + s * 2;        // o pair (oa, oa+1)
    const size_t e0 = (size_t)oa * ACT + ibase;
    const size_t e1 = e0 + ACT;

    v2f acc2[BATCH];
#pragma unroll
    for (int b = 0; b < BATCH; ++b) acc2[b] = (v2f){0.0f, 0.0f};

    // ---- scales (both branches, both o) ----
    float mq0 = mask_q[e0], mq1 = mask_q[e1];
    float mk0 = mask_k[e0], mk1 = mask_k[e1];
    float sb0 = scale_base[e0], sb1 = scale_base[e1];
    float ss0 = scale_sp[e0], ss1 = scale_sp[e1];
    v2f vbq = {mq0 * sb0, mq1 * sb1};
    v2f vbk = {mk0 * sb0, mk1 * sb1};
    v2f vsq = {mq0 * ss0, mq1 * ss1};
    v2f vsk = {mk0 * ss0, mk1 * ss1};

    v2f cs[8];
    // ================= q phase =================
    {
      const float4* c0p = reinterpret_cast<const float4*>(coef_q + e0 * 8);
      const float4* c1p = reinterpret_cast<const float4*>(coef_q + e1 * 8);
      float4 a0 = c0p[0], a1 = c0p[1];
      float4 b0 = c1p[0], b1 = c1p[1];
      cs[0] = (v2f){a0.x, b0.x} * vsq;
      cs[1] = (v2f){a0.y, b0.y} * vsq;
      cs[2] = (v2f){a0.z, b0.z} * vsq;
      cs[3] = (v2f){a0.w, b0.w} * vsq;
      cs[4] = (v2f){a1.x, b1.x} * vsq;
      cs[5] = (v2f){a1.y, b1.y} * vsq;
      cs[6] = (v2f){a1.z, b1.z} * vsq;
      cs[7] = (v2f){a1.w, b1.w} * vsq;
    }
#pragma unroll
    for (int b = 0; b < BATCH; ++b) {
      const float4 B0 = BsQ[(b * 2 + 0) * IBLK + l];
      const float4 B1 = BsQ[(b * 2 + 1) * IBLK + l];
      const float bs = basQ[b * IBLK + l];
      v2f a = acc2[b];
      a = fma2(cs[0], (v2f){B0.x, B0.x}, a);
      a = fma2(cs[1], (v2f){B0.y, B0.y}, a);
      a = fma2(cs[2], (v2f){B0.z, B0.z}, a);
      a = fma2(cs[3], (v2f){B0.w, B0.w}, a);
      a = fma2(cs[4], (v2f){B1.x, B1.x}, a);
      a = fma2(cs[5], (v2f){B1.y, B1.y}, a);
      a = fma2(cs[6], (v2f){B1.z, B1.z}, a);
      a = fma2(cs[7], (v2f){B1.w, B1.w}, a);
      a = fma2(vbq, (v2f){bs, bs}, a);
      acc2[b] = a;
      __builtin_amdgcn_sched_barrier(0);   // pin iteration (R4-R6 spill fix)
    }
    // ================= k phase =================
    {
      const float4* c0p = reinterpret_cast<const float4*>(coef_k + e0 * 8);
      const float4* c1p = reinterpret_cast<const float4*>(coef_k + e1 * 8);
      float4 a0 = c0p[0], a1 = c0p[1];
      float4 b0 = c1p[0], b1 = c1p[1];
      cs[0] = (v2f){a0.x, b0.x} * vsk;
      cs[1] = (v2f){a0.y, b0.y} * vsk;
      cs[2] = (v2f){a0.z, b0.z} * vsk;
      cs[3] = (v2f){a0.w, b0.w} * vsk;
      cs[4] = (v2f){a1.x, b1.x} * vsk;
      cs[5] = (v2f){a1.y, b1.y} * vsk;
      cs[6] = (v2f){a1.z, b1.z} * vsk;
      cs[7] = (v2f){a1.w, b1.w} * vsk;
    }
#pragma unroll
    for (int b = 0; b < BATCH; ++b) {
      const float4 B0 = BsK[(b * 2 + 0) * IBLK + l];
      const float4 B1 = BsK[(b * 2 + 1) * IBLK + l];
      const float bs = basK[b * IBLK + l];
      v2f a = acc2[b];
      a = fma2(cs[0], (v2f){B0.x, B0.x}, a);
      a = fma2(cs[1], (v2f){B0.y, B0.y}, a);
      a = fma2(cs[2], (v2f){B0.z, B0.z}, a);
      a = fma2(cs[3], (v2f){B0.w, B0.w}, a);
      a = fma2(cs[4], (v2f){B1.x, B1.x}, a);
      a = fma2(cs[5], (v2f){B1.y, B1.y}, a);
      a = fma2(cs[6], (v2f){B1.z, B1.z}, a);
      a = fma2(cs[7], (v2f){B1.w, B1.w}, a);
      a = fma2(vbk, (v2f){bs, bs}, a);
      acc2[b] = a;
      __builtin_amdgcn_sched_barrier(0);
    }

    // ---- fold reduction over 64 lanes (i): 7 swizzle-pairs instead of 24.
    // Level A (xor 1): keep b-low half on even lanes, high half on odd.
    v2f n0, n1, n2, n3;
    {
      const bool hi = (l & 1);
      v2f s0 = hi ? acc2[0] : acc2[4];
      v2f s1 = hi ? acc2[1] : acc2[5];
      v2f s2 = hi ? acc2[2] : acc2[6];
      v2f s3 = hi ? acc2[3] : acc2[7];
      v2f k0 = hi ? acc2[4] : acc2[0];
      v2f k1 = hi ? acc2[5] : acc2[1];
      v2f k2 = hi ? acc2[6] : acc2[2];
      v2f k3 = hi ? acc2[7] : acc2[3];
      n0 = k0 + shflx2(s0, 1);
      n1 = k1 + shflx2(s1, 1);
      n2 = k2 + shflx2(s2, 1);
      n3 = k3 + shflx2(s3, 1);
    }
    // Level B (xor 2)
    v2f m0, m1;
    {
      const bool hi = (l & 2);
      v2f s0 = hi ? n0 : n2;
      v2f s1 = hi ? n1 : n3;
      v2f k0 = hi ? n2 : n0;
      v2f k1 = hi ? n3 : n1;
      m0 = k0 + shflx2(s0, 2);
      m1 = k1 + shflx2(s1, 2);
    }
    // Level C (xor 4)
    v2f r;
    {
      const bool hi = (l & 4);
      v2f s0 = hi ? m0 : m1;
      v2f k0 = hi ? m1 : m0;
      r = k0 + shflx2(s0, 4);
    }
    // Stage 2: sum across the 8 octets. Lane l now holds b = bitrev3(l&7).
    r = r + shflx2(r, 8);
    r = r + shflx2(r, 16);
    r = r + shflx2(r, 32);

    if (l < 8) {
      y_part[(size_t)oa * (NIC * 8) + ic * 8 + l] = r.x;
      y_part[(size_t)(oa + 1) * (NIC * 8) + ic * 8 + l] = r.y;
    }
  }
}

// ---------------------------------------------------------------------------
// Kernel 3: sum 32 i-chunk partials per (o,b), add bias, softmax over groups
// of 8 outputs. One wave per output row (b,grp); 4 rows per 256-thread block.
// Slot for batch b is bitrev3(b) (the fold's output permutation).
// ---------------------------------------------------------------------------
__global__ void kan_softmax(const float* __restrict__ y_part,
                            const float* __restrict__ bias,
                            float* __restrict__ out) {
  const int t = threadIdx.x;
  const int wid = blockIdx.x * 4 + (t >> 6);   // row id, 0..2047
  const int b = wid >> 8;
  const int grp = wid & 255;
  const int l = t & 63;
  const int op = l >> 3;                       // o within group
  const int sub = l & 7;
  const int o = grp * 8 + op;
  const int slot = ((b & 1) << 2) | (b & 2) | ((b >> 2) & 1);  // bitrev3(b)

  float p = 0.0f;
#pragma unroll
  for (int j = 0; j < 4; ++j) {
    int icc = sub + 8 * j;
    p += y_part[(size_t)o * (NIC * 8) + icc * 8 + slot];
  }
  // sum the 8 sub-partials within each o-group (lanes 8*op .. 8*op+7)
#pragma unroll
  for (int off = 1; off < 8; off <<= 1) p += __shfl_xor(p, off);
  float v = p + bias[o];
  // softmax across the 8 o-groups (xor offs 8,16,32 span the groups)
  float m = v;
#pragma unroll
  for (int off = 8; off < 64; off <<= 1) m = fmaxf(m, __shfl_xor(m, off));
  float e = expf(v - m);
  float ssum = e;
#pragma unroll
  for (int off = 8; off < 64; off <<= 1) ssum += __shfl_xor(ssum, off);
  if (sub == 0) out[(size_t)b * ACT + o] = e / ssum;
}

// ---------------------------------------------------------------------------
// Workspace layout (floats):
//   y_part @ 0      : 524288  ([o][ic][slot], fully rewritten each call)
//   Bq     @ 524288 : 131072  ([ic][b*2+h][il] float4)
//   Bk     @ 655360 : 131072
//   baseq  @ 786432 : 16384   ([ic][b][il])
//   basek  @ 802816 : 16384
// total 819200 floats = 3.125 MiB. No init needed (every slot written).
// ---------------------------------------------------------------------------
extern "C" void kernel_launch(void* const* d_in, const int* in_sizes, int n_in,
                              void* d_out, int out_size, void* d_ws, size_t ws_size,
                              hipStream_t stream) {
  const float* q          = (const float*)d_in[0];
  const float* k          = (const float*)d_in[1];
  const float* coef_q     = (const float*)d_in[2];
  const float* coef_k     = (const float*)d_in[3];
  const float* scale_base = (const float*)d_in[4];
  const float* scale_sp   = (const float*)d_in[5];
  const float* mask_q     = (const float*)d_in[6];
  const float* mask_k     = (const float*)d_in[7];
  const float* bias_w     = (const float*)d_in[8];
  float* out = (float*)d_out;

  float* ws     = (float*)d_ws;
  float* y_part = ws;
  float* Bq     = ws + 524288;
  float* Bk     = Bq + 131072;
  float* baseq  = Bk + 131072;
  float* basek  = baseq + 16384;

  kan_precompute<<<dim3(64), dim3(256), 0, stream>>>(
      q, k, (float4*)Bq, (float4*)Bk, baseq, basek);
  kan_main<<<dim3(NOC * NIC), dim3(512), 0, stream>>>(
      coef_q, coef_k, scale_base, scale_sp, mask_q, mask_k,
      (const float4*)Bq, (const float4*)Bk, baseq, basek, y_part);
  kan_softmax<<<dim3(512), dim3(256), 0, stream>>>(y_part, bias_w, out);
}

// Round 9
// 79.772 us; speedup vs baseline: 1.0551x; 1.0551x over previous
//
#include <hip/hip_runtime.h>
#include <math.h>

// KAN attention: two spline-edge reductions (q,k branches) + bias + softmax(dim=8).
// batch=8, act_in=act_out=2048, C=8 coeffs/edge, N=4.19M edges/branch.
//
// R8 -> R9: R7==R8 in time despite halved LDS/VALU work => the wall is the 64
// per-wave sched_barrier(0) round trips (issue ds_reads -> lgkmcnt(0) ~120cy
// unhidden -> FMA), not any pipe (VALU 12.6%, LDS ~26%, HBM 20%). Fix: pin
// ONLY the DS classes -- sched_barrier(0x7F) lets VALU/VMEM cross (FMAs of
// iter b sink below the fence, k-branch loads hoist above the q-loop) while
// ds_reads stay in their iteration window (bounded ~2-iter lookahead, no
// unbounded-hoist spill of R4-R6). Everything else identical to R8.

#define ACT 2048
#define BATCH 8
#define IBLK 64               // i per block (= lanes of one wave)
#define NIC (ACT / IBLK)      // 32 i-chunks
#define OBLK 64               // o per block
#define NOC (ACT / OBLK)      // 32 o-chunks

// sched_barrier mask: allow ALU|VALU|SALU|MFMA|VMEM|VMEM_READ|VMEM_WRITE to
// cross; pin DS(0x80)/DS_READ(0x100)/DS_WRITE(0x200).
#define SBAR_PIN_DS() __builtin_amdgcn_sched_barrier(0x7F)

typedef float v2f __attribute__((ext_vector_type(2)));

__device__ __forceinline__ v2f fma2(v2f a, v2f b, v2f c) {
  return __builtin_elementwise_fma(a, b, c);
}
__device__ __forceinline__ v2f shflx2(v2f v, int m) {
  v2f r;
  r.x = __shfl_xor(v.x, m);
  r.y = __shfl_xor(v.y, m);
  return r;
}

// ---------------------------------------------------------------------------
// Kernel 1: B-spline basis (Cox-de Boor, k=3, 12 uniform knots at -2.2+0.4j)
// and silu(x) for all (b,i) of both branches.
// Layout: B[ic][b*2+h][il] as float4 (ic=i/64, il=i%64), base[ic][b][il].
// ---------------------------------------------------------------------------
__global__ void kan_precompute(const float* __restrict__ q, const float* __restrict__ k,
                               float4* __restrict__ Bq, float4* __restrict__ Bk,
                               float* __restrict__ baseq, float* __restrict__ basek) {
  int tid = blockIdx.x * blockDim.x + threadIdx.x;
  if (tid >= ACT * BATCH) return;
  int il = tid & (IBLK - 1);
  int b = (tid >> 6) & 7;
  int ic = tid >> 9;
  int i = ic * IBLK + il;
  const float t0 = -2.2f;
  const float h = 0.4f;
  for (int br = 0; br < 2; ++br) {
    const float* xsrc = br ? k : q;
    float4* Bdst = br ? Bk : Bq;
    float* basedst = br ? basek : baseq;
    float x = xsrc[(size_t)b * ACT + i];
    float Bv[11];
#pragma unroll
    for (int j = 0; j < 11; ++j) {
      float tj = t0 + h * (float)j;
      float tj1 = t0 + h * (float)(j + 1);
      Bv[j] = (x >= tj && x < tj1) ? 1.0f : 0.0f;
    }
#pragma unroll
    for (int d = 1; d <= 3; ++d) {
      float inv = 1.0f / (h * (float)d);
#pragma unroll
      for (int j = 0; j + d < 11; ++j) {
        float tj = t0 + h * (float)j;
        float tjd1 = t0 + h * (float)(j + d + 1);
        Bv[j] = (x - tj) * inv * Bv[j] + (tjd1 - x) * inv * Bv[j + 1];
      }
    }
    Bdst[((size_t)ic * 16 + b * 2 + 0) * IBLK + il] = make_float4(Bv[0], Bv[1], Bv[2], Bv[3]);
    Bdst[((size_t)ic * 16 + b * 2 + 1) * IBLK + il] = make_float4(Bv[4], Bv[5], Bv[6], Bv[7]);
    basedst[((size_t)ic * 8 + b) * IBLK + il] = x / (1.0f + expf(-x));
  }
}

// ---------------------------------------------------------------------------
// Kernel 2: main reduction. 1024 blocks x 512 threads, 4 blocks/CU (36 KB
// LDS) -> 32 waves/CU. Block = (ic: 64 i) x (oc: 64 o); wave w handles an
// o-PAIR per step, 4 steps, no barriers in the loop. Per step: q-phase
// (load+scale-fold q coef, 8 b-iters of packed FMA vs LDS B), k-phase (same
// with k), then a 7+3-swizzle fold reduction and a 2-float store per lane<8.
// acc2[b] = {y_o0, y_o1} partial; B element broadcast into both pk lanes.
// DS-pinning sched_barrier(0x7F) per b-iteration: prevents the unbounded
// ds_read hoist (R4-R6 spill) but allows FMA sink + VMEM hoist (R9 fix).
// ---------------------------------------------------------------------------
__global__ __launch_bounds__(512, 8) void kan_main(
    const float* __restrict__ coef_q, const float* __restrict__ coef_k,
    const float* __restrict__ scale_base, const float* __restrict__ scale_sp,
    const float* __restrict__ mask_q, const float* __restrict__ mask_k,
    const float4* __restrict__ Bq, const float4* __restrict__ Bk,
    const float* __restrict__ baseq, const float* __restrict__ basek,
    float* __restrict__ y_part) {
  __shared__ float4 BsQ[16 * IBLK];   // [(b*2+h)*64 + il]
  __shared__ float4 BsK[16 * IBLK];
  __shared__ float basQ[8 * IBLK];    // [b*64 + il]
  __shared__ float basK[8 * IBLK];

  const int t = threadIdx.x;
  const int l = t & 63;               // lane = i within chunk
  const int w = t >> 6;               // wave index (0..7)
  const int oc = blockIdx.x >> 5;
  const int ic = blockIdx.x & 31;
  const int o0 = oc * OBLK;
  const size_t ibase = (size_t)ic * IBLK + l;

  // ---- stage B/base for both branches (once per block lifetime) ----
  {
    const float4* srcq = Bq + (size_t)ic * 16 * IBLK;
    const float4* srck = Bk + (size_t)ic * 16 * IBLK;
#pragma unroll
    for (int r = 0; r < 2; ++r) {
      BsQ[r * 512 + t] = srcq[r * 512 + t];
      BsK[r * 512 + t] = srck[r * 512 + t];
    }
    if (t < 128) {
      reinterpret_cast<float4*>(basQ)[t] =
          reinterpret_cast<const float4*>(baseq + (size_t)ic * 8 * IBLK)[t];
    } else if (t < 256) {
      reinterpret_cast<float4*>(basK)[t - 128] =
          reinterpret_cast<const float4*>(basek + (size_t)ic * 8 * IBLK)[t - 128];
    }
  }
  __syncthreads();

#pragma unroll 1
  for (int s = 0; s < 4; ++s) {
    const int oa = o0 + w * 8 + s * 2;        // o pair (oa, oa+1)
    const size_t e0 = (size_t)oa * ACT + ibase;
    const size_t e1 = e0 + ACT;

    v2f acc2[BATCH];
#pragma unroll
    for (int b = 0; b < BATCH; ++b) acc2[b] = (v2f){0.0f, 0.0f};

    // ---- scales (both branches, both o) ----
    float mq0 = mask_q[e0], mq1 = mask_q[e1];
    float mk0 = mask_k[e0], mk1 = mask_k[e1];
    float sb0 = scale_base[e0], sb1 = scale_base[e1];
    float ss0 = scale_sp[e0], ss1 = scale_sp[e1];
    v2f vbq = {mq0 * sb0, mq1 * sb1};
    v2f vbk = {mk0 * sb0, mk1 * sb1};
    v2f vsq = {mq0 * ss0, mq1 * ss1};
    v2f vsk = {mk0 * ss0, mk1 * ss1};

    v2f cs[8];
    // ================= q phase =================
    {
      const float4* c0p = reinterpret_cast<const float4*>(coef_q + e0 * 8);
      const float4* c1p = reinterpret_cast<const float4*>(coef_q + e1 * 8);
      float4 a0 = c0p[0], a1 = c0p[1];
      float4 b0 = c1p[0], b1 = c1p[1];
      cs[0] = (v2f){a0.x, b0.x} * vsq;
      cs[1] = (v2f){a0.y, b0.y} * vsq;
      cs[2] = (v2f){a0.z, b0.z} * vsq;
      cs[3] = (v2f){a0.w, b0.w} * vsq;
      cs[4] = (v2f){a1.x, b1.x} * vsq;
      cs[5] = (v2f){a1.y, b1.y} * vsq;
      cs[6] = (v2f){a1.z, b1.z} * vsq;
      cs[7] = (v2f){a1.w, b1.w} * vsq;
    }
#pragma unroll
    for (int b = 0; b < BATCH; ++b) {
      const float4 B0 = BsQ[(b * 2 + 0) * IBLK + l];
      const float4 B1 = BsQ[(b * 2 + 1) * IBLK + l];
      const float bs = basQ[b * IBLK + l];
      v2f a = acc2[b];
      a = fma2(cs[0], (v2f){B0.x, B0.x}, a);
      a = fma2(cs[1], (v2f){B0.y, B0.y}, a);
      a = fma2(cs[2], (v2f){B0.z, B0.z}, a);
      a = fma2(cs[3], (v2f){B0.w, B0.w}, a);
      a = fma2(cs[4], (v2f){B1.x, B1.x}, a);
      a = fma2(cs[5], (v2f){B1.y, B1.y}, a);
      a = fma2(cs[6], (v2f){B1.z, B1.z}, a);
      a = fma2(cs[7], (v2f){B1.w, B1.w}, a);
      a = fma2(vbq, (v2f){bs, bs}, a);
      acc2[b] = a;
      SBAR_PIN_DS();   // pin ds_reads to their iteration; VALU/VMEM may cross
    }
    // ================= k phase =================
    {
      const float4* c0p = reinterpret_cast<const float4*>(coef_k + e0 * 8);
      const float4* c1p = reinterpret_cast<const float4*>(coef_k + e1 * 8);
      float4 a0 = c0p[0], a1 = c0p[1];
      float4 b0 = c1p[0], b1 = c1p[1];
      cs[0] = (v2f){a0.x, b0.x} * vsk;
      cs[1] = (v2f){a0.y, b0.y} * vsk;
      cs[2] = (v2f){a0.z, b0.z} * vsk;
      cs[3] = (v2f){a0.w, b0.w} * vsk;
      cs[4] = (v2f){a1.x, b1.x} * vsk;
      cs[5] = (v2f){a1.y, b1.y} * vsk;
      cs[6] = (v2f){a1.z, b1.z} * vsk;
      cs[7] = (v2f){a1.w, b1.w} * vsk;
    }
#pragma unroll
    for (int b = 0; b < BATCH; ++b) {
      const float4 B0 = BsK[(b * 2 + 0) * IBLK + l];
      const float4 B1 = BsK[(b * 2 + 1) * IBLK + l];
      const float bs = basK[b * IBLK + l];
      v2f a = acc2[b];
      a = fma2(cs[0], (v2f){B0.x, B0.x}, a);
      a = fma2(cs[1], (v2f){B0.y, B0.y}, a);
      a = fma2(cs[2], (v2f){B0.z, B0.z}, a);
      a = fma2(cs[3], (v2f){B0.w, B0.w}, a);
      a = fma2(cs[4], (v2f){B1.x, B1.x}, a);
      a = fma2(cs[5], (v2f){B1.y, B1.y}, a);
      a = fma2(cs[6], (v2f){B1.z, B1.z}, a);
      a = fma2(cs[7], (v2f){B1.w, B1.w}, a);
      a = fma2(vbk, (v2f){bs, bs}, a);
      acc2[b] = a;
      SBAR_PIN_DS();
    }

    // ---- fold reduction over 64 lanes (i): 7 swizzle-pairs instead of 24.
    // Level A (xor 1): keep b-low half on even lanes, high half on odd.
    v2f n0, n1, n2, n3;
    {
      const bool hi = (l & 1);
      v2f s0 = hi ? acc2[0] : acc2[4];
      v2f s1 = hi ? acc2[1] : acc2[5];
      v2f s2 = hi ? acc2[2] : acc2[6];
      v2f s3 = hi ? acc2[3] : acc2[7];
      v2f k0 = hi ? acc2[4] : acc2[0];
      v2f k1 = hi ? acc2[5] : acc2[1];
      v2f k2 = hi ? acc2[6] : acc2[2];
      v2f k3 = hi ? acc2[7] : acc2[3];
      n0 = k0 + shflx2(s0, 1);
      n1 = k1 + shflx2(s1, 1);
      n2 = k2 + shflx2(s2, 1);
      n3 = k3 + shflx2(s3, 1);
    }
    // Level B (xor 2)
    v2f m0, m1;
    {
      const bool hi = (l & 2);
      v2f s0 = hi ? n0 : n2;
      v2f s1 = hi ? n1 : n3;
      v2f k0 = hi ? n2 : n0;
      v2f k1 = hi ? n3 : n1;
      m0 = k0 + shflx2(s0, 2);
      m1 = k1 + shflx2(s1, 2);
    }
    // Level C (xor 4)
    v2f r;
    {
      const bool hi = (l & 4);
      v2f s0 = hi ? m0 : m1;
      v2f k0 = hi ? m1 : m0;
      r = k0 + shflx2(s0, 4);
    }
    // Stage 2: sum across the 8 octets. Lane l now holds b = bitrev3(l&7).
    r = r + shflx2(r, 8);
    r = r + shflx2(r, 16);
    r = r + shflx2(r, 32);

    if (l < 8) {
      y_part[(size_t)oa * (NIC * 8) + ic * 8 + l] = r.x;
      y_part[(size_t)(oa + 1) * (NIC * 8) + ic * 8 + l] = r.y;
    }
  }
}

// ---------------------------------------------------------------------------
// Kernel 3: sum 32 i-chunk partials per (o,b), add bias, softmax over groups
// of 8 outputs. One wave per output row (b,grp); 4 rows per 256-thread block.
// Slot for batch b is bitrev3(b) (the fold's output permutation).
// ---------------------------------------------------------------------------
__global__ void kan_softmax(const float* __restrict__ y_part,
                            const float* __restrict__ bias,
                            float* __restrict__ out) {
  const int t = threadIdx.x;
  const int wid = blockIdx.x * 4 + (t >> 6);   // row id, 0..2047
  const int b = wid >> 8;
  const int grp = wid & 255;
  const int l = t & 63;
  const int op = l >> 3;                       // o within group
  const int sub = l & 7;
  const int o = grp * 8 + op;
  const int slot = ((b & 1) << 2) | (b & 2) | ((b >> 2) & 1);  // bitrev3(b)

  float p = 0.0f;
#pragma unroll
  for (int j = 0; j < 4; ++j) {
    int icc = sub + 8 * j;
    p += y_part[(size_t)o * (NIC * 8) + icc * 8 + slot];
  }
  // sum the 8 sub-partials within each o-group (lanes 8*op .. 8*op+7)
#pragma unroll
  for (int off = 1; off < 8; off <<= 1) p += __shfl_xor(p, off);
  float v = p + bias[o];
  // softmax across the 8 o-groups (xor offs 8,16,32 span the groups)
  float m = v;
#pragma unroll
  for (int off = 8; off < 64; off <<= 1) m = fmaxf(m, __shfl_xor(m, off));
  float e = expf(v - m);
  float ssum = e;
#pragma unroll
  for (int off = 8; off < 64; off <<= 1) ssum += __shfl_xor(ssum, off);
  if (sub == 0) out[(size_t)b * ACT + o] = e / ssum;
}

// ---------------------------------------------------------------------------
// Workspace layout (floats):
//   y_part @ 0      : 524288  ([o][ic][slot], fully rewritten each call)
//   Bq     @ 524288 : 131072  ([ic][b*2+h][il] float4)
//   Bk     @ 655360 : 131072
//   baseq  @ 786432 : 16384   ([ic][b][il])
//   basek  @ 802816 : 16384
// total 819200 floats = 3.125 MiB. No init needed (every slot written).
// ---------------------------------------------------------------------------
extern "C" void kernel_launch(void* const* d_in, const int* in_sizes, int n_in,
                              void* d_out, int out_size, void* d_ws, size_t ws_size,
                              hipStream_t stream) {
  const float* q          = (const float*)d_in[0];
  const float* k          = (const float*)d_in[1];
  const float* coef_q     = (const float*)d_in[2];
  const float* coef_k     = (const float*)d_in[3];
  const float* scale_base = (const float*)d_in[4];
  const float* scale_sp   = (const float*)d_in[5];
  const float* mask_q     = (const float*)d_in[6];
  const float* mask_k     = (const float*)d_in[7];
  const float* bias_w     = (const float*)d_in[8];
  float* out = (float*)d_out;

  float* ws     = (float*)d_ws;
  float* y_part = ws;
  float* Bq     = ws + 524288;
  float* Bk     = Bq + 131072;
  float* baseq  = Bk + 131072;
  float* basek  = baseq + 16384;

  kan_precompute<<<dim3(64), dim3(256), 0, stream>>>(
      q, k, (float4*)Bq, (float4*)Bk, baseq, basek);
  kan_main<<<dim3(NOC * NIC), dim3(512), 0, stream>>>(
      coef_q, coef_k, scale_base, scale_sp, mask_q, mask_k,
      (const float4*)Bq, (const float4*)Bk, baseq, basek, y_part);
  kan_softmax<<<dim3(512), dim3(256), 0, stream>>>(y_part, bias_w, out);
}

// Round 10
// 74.411 us; speedup vs baseline: 1.1311x; 1.0720x over previous
//
#include <hip/hip_runtime.h>
#include <math.h>

// KAN attention: two spline-edge reductions (q,k branches) + bias + softmax(dim=8).
// batch=8, act_in=act_out=2048, C=8 coeffs/edge, N=4.19M edges/branch.
//
// R9 -> R10: R9 is delivery/latency-bound (effective 4.8 TB/s logical, all
// pipes <50%; per-step first-use waits on same-step loads, no cross-iteration
// hoist through the unroll-1 back edge; no reg room at the 64-VGPR/8-wave
// budget). R10: 256-thread blocks, plain launch_bounds(256) -> 128-VGPR
// budget (R2 precedent), 16 waves/CU, and an explicit two-buffer software
// pipeline: LOAD(next step) issued before COMPUTE(current), cs-fold done in
// place over the coef buffer. Per-step VMEM exposure ~0. LDS/VALU per-CU
// totals unchanged from R9.

#define ACT 2048
#define BATCH 8
#define IBLK 64               // i per block (= lanes of one wave)
#define NIC (ACT / IBLK)      // 32 i-chunks
#define OBLK 64               // o per block
#define NOC (ACT / OBLK)      // 32 o-chunks

// sched_barrier mask: allow ALU|VALU|SALU|MFMA|VMEM to cross; pin DS classes.
#define SBAR_PIN_DS() __builtin_amdgcn_sched_barrier(0x7F)

typedef float v2f __attribute__((ext_vector_type(2)));

__device__ __forceinline__ v2f fma2(v2f a, v2f b, v2f c) {
  return __builtin_elementwise_fma(a, b, c);
}
__device__ __forceinline__ v2f shflx2(v2f v, int m) {
  v2f r;
  r.x = __shfl_xor(v.x, m);
  r.y = __shfl_xor(v.y, m);
  return r;
}

// ---------------------------------------------------------------------------
// Kernel 1: B-spline basis (Cox-de Boor, k=3, 12 uniform knots at -2.2+0.4j)
// and silu(x) for all (b,i) of both branches.
// Layout: B[ic][b*2+h][il] as float4 (ic=i/64, il=i%64), base[ic][b][il].
// ---------------------------------------------------------------------------
__global__ void kan_precompute(const float* __restrict__ q, const float* __restrict__ k,
                               float4* __restrict__ Bq, float4* __restrict__ Bk,
                               float* __restrict__ baseq, float* __restrict__ basek) {
  int tid = blockIdx.x * blockDim.x + threadIdx.x;
  if (tid >= ACT * BATCH) return;
  int il = tid & (IBLK - 1);
  int b = (tid >> 6) & 7;
  int ic = tid >> 9;
  int i = ic * IBLK + il;
  const float t0 = -2.2f;
  const float h = 0.4f;
  for (int br = 0; br < 2; ++br) {
    const float* xsrc = br ? k : q;
    float4* Bdst = br ? Bk : Bq;
    float* basedst = br ? basek : baseq;
    float x = xsrc[(size_t)b * ACT + i];
    float Bv[11];
#pragma unroll
    for (int j = 0; j < 11; ++j) {
      float tj = t0 + h * (float)j;
      float tj1 = t0 + h * (float)(j + 1);
      Bv[j] = (x >= tj && x < tj1) ? 1.0f : 0.0f;
    }
#pragma unroll
    for (int d = 1; d <= 3; ++d) {
      float inv = 1.0f / (h * (float)d);
#pragma unroll
      for (int j = 0; j + d < 11; ++j) {
        float tj = t0 + h * (float)j;
        float tjd1 = t0 + h * (float)(j + d + 1);
        Bv[j] = (x - tj) * inv * Bv[j] + (tjd1 - x) * inv * Bv[j + 1];
      }
    }
    Bdst[((size_t)ic * 16 + b * 2 + 0) * IBLK + il] = make_float4(Bv[0], Bv[1], Bv[2], Bv[3]);
    Bdst[((size_t)ic * 16 + b * 2 + 1) * IBLK + il] = make_float4(Bv[4], Bv[5], Bv[6], Bv[7]);
    basedst[((size_t)ic * 8 + b) * IBLK + il] = x / (1.0f + expf(-x));
  }
}

// ---------------------------------------------------------------------------
// Kernel 2: main reduction. 1024 blocks x 256 threads, 4 blocks/CU (36 KB
// LDS) -> 16 waves/CU at a 128-VGPR budget. Block = (ic: 64 i) x (oc: 64 o);
// wave w owns 16 o's = 8 steps x o-pair. Two-buffer software pipeline: loads
// of step s+1 in flight during compute of step s. Per step: q-phase + k-phase
// of packed FMA vs LDS B (cs folded in place over the coef buffer), 7+3
// swizzle fold reduction, 2-float store per lane<8. DS-pinning
// sched_barrier(0x7F) per b-iteration (anti-hoist, R4-R6 spill fix).
// ---------------------------------------------------------------------------
__global__ __launch_bounds__(256) void kan_main(
    const float* __restrict__ coef_q, const float* __restrict__ coef_k,
    const float* __restrict__ scale_base, const float* __restrict__ scale_sp,
    const float* __restrict__ mask_q, const float* __restrict__ mask_k,
    const float4* __restrict__ Bq, const float4* __restrict__ Bk,
    const float* __restrict__ baseq, const float* __restrict__ basek,
    float* __restrict__ y_part) {
  __shared__ float4 BsQ[16 * IBLK];   // [(b*2+h)*64 + il]
  __shared__ float4 BsK[16 * IBLK];
  __shared__ float basQ[8 * IBLK];    // [b*64 + il]
  __shared__ float basK[8 * IBLK];

  const int t = threadIdx.x;
  const int l = t & 63;               // lane = i within chunk
  const int w = t >> 6;               // wave index (0..3)
  const int oc = blockIdx.x >> 5;
  const int ic = blockIdx.x & 31;
  const int o0 = oc * OBLK;
  const size_t ibase = (size_t)ic * IBLK + l;

  // ---- stage B/base for both branches (once per block lifetime) ----
  {
    const float4* srcq = Bq + (size_t)ic * 16 * IBLK;
    const float4* srck = Bk + (size_t)ic * 16 * IBLK;
#pragma unroll
    for (int r = 0; r < 4; ++r) {
      BsQ[r * 256 + t] = srcq[r * 256 + t];
      BsK[r * 256 + t] = srck[r * 256 + t];
    }
    if (t < 128) {
      reinterpret_cast<float4*>(basQ)[t] =
          reinterpret_cast<const float4*>(baseq + (size_t)ic * 8 * IBLK)[t];
    } else {
      reinterpret_cast<float4*>(basK)[t - 128] =
          reinterpret_cast<const float4*>(basek + (size_t)ic * 8 * IBLK)[t - 128];
    }
  }
  __syncthreads();

  // Two prefetch buffers: coef q (4 float4), coef k (4 float4), 8 scalars.
  float4 cqA[4], ckA[4], cqB[4], ckB[4];
  float scA[8], scB[8];

#define LOAD(BUF, S)                                                          \
  {                                                                           \
    const int oa_ = o0 + w * 16 + (S) * 2;                                    \
    const size_t e0_ = (size_t)oa_ * ACT + ibase;                             \
    const size_t e1_ = e0_ + ACT;                                             \
    const float4* p0 = reinterpret_cast<const float4*>(coef_q + e0_ * 8);     \
    const float4* p1 = reinterpret_cast<const float4*>(coef_q + e1_ * 8);     \
    cq##BUF[0] = p0[0]; cq##BUF[1] = p0[1];                                   \
    cq##BUF[2] = p1[0]; cq##BUF[3] = p1[1];                                   \
    const float4* r0 = reinterpret_cast<const float4*>(coef_k + e0_ * 8);     \
    const float4* r1 = reinterpret_cast<const float4*>(coef_k + e1_ * 8);     \
    ck##BUF[0] = r0[0]; ck##BUF[1] = r0[1];                                   \
    ck##BUF[2] = r1[0]; ck##BUF[3] = r1[1];                                   \
    sc##BUF[0] = mask_q[e0_];     sc##BUF[1] = mask_q[e1_];                   \
    sc##BUF[2] = mask_k[e0_];     sc##BUF[3] = mask_k[e1_];                   \
    sc##BUF[4] = scale_base[e0_]; sc##BUF[5] = scale_base[e1_];               \
    sc##BUF[6] = scale_sp[e0_];   sc##BUF[7] = scale_sp[e1_];                 \
  }

#define COMPUTE(BUF, S)                                                       \
  {                                                                           \
    const int oa_ = o0 + w * 16 + (S) * 2;                                    \
    v2f vbq = {sc##BUF[0] * sc##BUF[4], sc##BUF[1] * sc##BUF[5]};             \
    v2f vbk = {sc##BUF[2] * sc##BUF[4], sc##BUF[3] * sc##BUF[5]};             \
    v2f vsq = {sc##BUF[0] * sc##BUF[6], sc##BUF[1] * sc##BUF[7]};             \
    v2f vsk = {sc##BUF[2] * sc##BUF[6], sc##BUF[3] * sc##BUF[7]};             \
    v2f acc2[BATCH];                                                          \
    _Pragma("unroll") for (int b = 0; b < BATCH; ++b)                         \
        acc2[b] = (v2f){0.0f, 0.0f};                                          \
    v2f cs[8];                                                                \
    cs[0] = (v2f){cq##BUF[0].x, cq##BUF[2].x} * vsq;                          \
    cs[1] = (v2f){cq##BUF[0].y, cq##BUF[2].y} * vsq;                          \
    cs[2] = (v2f){cq##BUF[0].z, cq##BUF[2].z} * vsq;                          \
    cs[3] = (v2f){cq##BUF[0].w, cq##BUF[2].w} * vsq;                          \
    cs[4] = (v2f){cq##BUF[1].x, cq##BUF[3].x} * vsq;                          \
    cs[5] = (v2f){cq##BUF[1].y, cq##BUF[3].y} * vsq;                          \
    cs[6] = (v2f){cq##BUF[1].z, cq##BUF[3].z} * vsq;                          \
    cs[7] = (v2f){cq##BUF[1].w, cq##BUF[3].w} * vsq;                          \
    _Pragma("unroll") for (int b = 0; b < BATCH; ++b) {                       \
      const float4 B0 = BsQ[(b * 2 + 0) * IBLK + l];                          \
      const float4 B1 = BsQ[(b * 2 + 1) * IBLK + l];                          \
      const float bs = basQ[b * IBLK + l];                                    \
      v2f a = acc2[b];                                                        \
      a = fma2(cs[0], (v2f){B0.x, B0.x}, a);                                  \
      a = fma2(cs[1], (v2f){B0.y, B0.y}, a);                                  \
      a = fma2(cs[2], (v2f){B0.z, B0.z}, a);                                  \
      a = fma2(cs[3], (v2f){B0.w, B0.w}, a);                                  \
      a = fma2(cs[4], (v2f){B1.x, B1.x}, a);                                  \
      a = fma2(cs[5], (v2f){B1.y, B1.y}, a);                                  \
      a = fma2(cs[6], (v2f){B1.z, B1.z}, a);                                  \
      a = fma2(cs[7], (v2f){B1.w, B1.w}, a);                                  \
      a = fma2(vbq, (v2f){bs, bs}, a);                                        \
      acc2[b] = a;                                                            \
      SBAR_PIN_DS();                                                          \
    }                                                                         \
    cs[0] = (v2f){ck##BUF[0].x, ck##BUF[2].x} * vsk;                          \
    cs[1] = (v2f){ck##BUF[0].y, ck##BUF[2].y} * vsk;                          \
    cs[2] = (v2f){ck##BUF[0].z, ck##BUF[2].z} * vsk;                          \
    cs[3] = (v2f){ck##BUF[0].w, ck##BUF[2].w} * vsk;                          \
    cs[4] = (v2f){ck##BUF[1].x, ck##BUF[3].x} * vsk;                          \
    cs[5] = (v2f){ck##BUF[1].y, ck##BUF[3].y} * vsk;                          \
    cs[6] = (v2f){ck##BUF[1].z, ck##BUF[3].z} * vsk;                          \
    cs[7] = (v2f){ck##BUF[1].w, ck##BUF[3].w} * vsk;                          \
    _Pragma("unroll") for (int b = 0; b < BATCH; ++b) {                       \
      const float4 B0 = BsK[(b * 2 + 0) * IBLK + l];                          \
      const float4 B1 = BsK[(b * 2 + 1) * IBLK + l];                          \
      const float bs = basK[b * IBLK + l];                                    \
      v2f a = acc2[b];                                                        \
      a = fma2(cs[0], (v2f){B0.x, B0.x}, a);                                  \
      a = fma2(cs[1], (v2f){B0.y, B0.y}, a);                                  \
      a = fma2(cs[2], (v2f){B0.z, B0.z}, a);                                  \
      a = fma2(cs[3], (v2f){B0.w, B0.w}, a);                                  \
      a = fma2(cs[4], (v2f){B1.x, B1.x}, a);                                  \
      a = fma2(cs[5], (v2f){B1.y, B1.y}, a);                                  \
      a = fma2(cs[6], (v2f){B1.z, B1.z}, a);                                  \
      a = fma2(cs[7], (v2f){B1.w, B1.w}, a);                                  \
      a = fma2(vbk, (v2f){bs, bs}, a);                                        \
      acc2[b] = a;                                                            \
      SBAR_PIN_DS();                                                          \
    }                                                                         \
    /* fold reduction over 64 lanes: 7 swizzle-pairs + 3 octet levels */      \
    v2f n0, n1, n2, n3;                                                       \
    {                                                                         \
      const bool hi = (l & 1);                                                \
      v2f s0 = hi ? acc2[0] : acc2[4];                                        \
      v2f s1 = hi ? acc2[1] : acc2[5];                                        \
      v2f s2 = hi ? acc2[2] : acc2[6];                                        \
      v2f s3 = hi ? acc2[3] : acc2[7];                                        \
      v2f k0 = hi ? acc2[4] : acc2[0];                                        \
      v2f k1 = hi ? acc2[5] : acc2[1];                                        \
      v2f k2 = hi ? acc2[6] : acc2[2];                                        \
      v2f k3 = hi ? acc2[7] : acc2[3];                                        \
      n0 = k0 + shflx2(s0, 1);                                                \
      n1 = k1 + shflx2(s1, 1);                                                \
      n2 = k2 + shflx2(s2, 1);                                                \
      n3 = k3 + shflx2(s3, 1);                                                \
    }                                                                         \
    v2f m0, m1;                                                               \
    {                                                                         \
      const bool hi = (l & 2);                                                \
      v2f s0 = hi ? n0 : n2;                                                  \
      v2f s1 = hi ? n1 : n3;                                                  \
      v2f k0 = hi ? n2 : n0;                                                  \
      v2f k1 = hi ? n3 : n1;                                                  \
      m0 = k0 + shflx2(s0, 2);                                                \
      m1 = k1 + shflx2(s1, 2);                                                \
    }                                                                         \
    v2f r;                                                                    \
    {                                                                         \
      const bool hi = (l & 4);                                                \
      v2f s0 = hi ? m0 : m1;                                                  \
      v2f k0 = hi ? m1 : m0;                                                  \
      r = k0 + shflx2(s0, 4);                                                 \
    }                                                                         \
    r = r + shflx2(r, 8);                                                     \
    r = r + shflx2(r, 16);                                                    \
    r = r + shflx2(r, 32);                                                    \
    if (l < 8) {                                                              \
      y_part[(size_t)oa_ * (NIC * 8) + ic * 8 + l] = r.x;                     \
      y_part[(size_t)(oa_ + 1) * (NIC * 8) + ic * 8 + l] = r.y;               \
    }                                                                         \
  }

  LOAD(A, 0)
#pragma unroll 1
  for (int ss = 0; ss < 4; ++ss) {
    const int s0 = ss * 2;
    LOAD(B, s0 + 1)        // in flight during COMPUTE(A)
    COMPUTE(A, s0)
    if (ss < 3) LOAD(A, s0 + 2)   // in flight during COMPUTE(B)
    COMPUTE(B, s0 + 1)
  }
#undef LOAD
#undef COMPUTE
}

// ---------------------------------------------------------------------------
// Kernel 3: sum 32 i-chunk partials per (o,b), add bias, softmax over groups
// of 8 outputs. One wave per output row (b,grp); 4 rows per 256-thread block.
// Slot for batch b is bitrev3(b) (the fold's output permutation).
// ---------------------------------------------------------------------------
__global__ void kan_softmax(const float* __restrict__ y_part,
                            const float* __restrict__ bias,
                            float* __restrict__ out) {
  const int t = threadIdx.x;
  const int wid = blockIdx.x * 4 + (t >> 6);   // row id, 0..2047
  const int b = wid >> 8;
  const int grp = wid & 255;
  const int l = t & 63;
  const int op = l >> 3;                       // o within group
  const int sub = l & 7;
  const int o = grp * 8 + op;
  const int slot = ((b & 1) << 2) | (b & 2) | ((b >> 2) & 1);  // bitrev3(b)

  float p = 0.0f;
#pragma unroll
  for (int j = 0; j < 4; ++j) {
    int icc = sub + 8 * j;
    p += y_part[(size_t)o * (NIC * 8) + icc * 8 + slot];
  }
#pragma unroll
  for (int off = 1; off < 8; off <<= 1) p += __shfl_xor(p, off);
  float v = p + bias[o];
  float m = v;
#pragma unroll
  for (int off = 8; off < 64; off <<= 1) m = fmaxf(m, __shfl_xor(m, off));
  float e = expf(v - m);
  float ssum = e;
#pragma unroll
  for (int off = 8; off < 64; off <<= 1) ssum += __shfl_xor(ssum, off);
  if (sub == 0) out[(size_t)b * ACT + o] = e / ssum;
}

// ---------------------------------------------------------------------------
// Workspace layout (floats):
//   y_part @ 0      : 524288  ([o][ic][slot], fully rewritten each call)
//   Bq     @ 524288 : 131072  ([ic][b*2+h][il] float4)
//   Bk     @ 655360 : 131072
//   baseq  @ 786432 : 16384   ([ic][b][il])
//   basek  @ 802816 : 16384
// total 819200 floats = 3.125 MiB. No init needed (every slot written).
// ---------------------------------------------------------------------------
extern "C" void kernel_launch(void* const* d_in, const int* in_sizes, int n_in,
                              void* d_out, int out_size, void* d_ws, size_t ws_size,
                              hipStream_t stream) {
  const float* q          = (const float*)d_in[0];
  const float* k          = (const float*)d_in[1];
  const float* coef_q     = (const float*)d_in[2];
  const float* coef_k     = (const float*)d_in[3];
  const float* scale_base = (const float*)d_in[4];
  const float* scale_sp   = (const float*)d_in[5];
  const float* mask_q     = (const float*)d_in[6];
  const float* mask_k     = (const float*)d_in[7];
  const float* bias_w     = (const float*)d_in[8];
  float* out = (float*)d_out;

  float* ws     = (float*)d_ws;
  float* y_part = ws;
  float* Bq     = ws + 524288;
  float* Bk     = Bq + 131072;
  float* baseq  = Bk + 131072;
  float* basek  = baseq + 16384;

  kan_precompute<<<dim3(64), dim3(256), 0, stream>>>(
      q, k, (float4*)Bq, (float4*)Bk, baseq, basek);
  kan_main<<<dim3(NOC * NIC), dim3(256), 0, stream>>>(
      coef_q, coef_k, scale_base, scale_sp, mask_q, mask_k,
      (const float4*)Bq, (const float4*)Bk, baseq, basek, y_part);
  kan_softmax<<<dim3(512), dim3(256), 0, stream>>>(y_part, bias_w, out);
}